// Round 3
// baseline (226.413 us; speedup 1.0000x reference)
//
#include <hip/hip_runtime.h>

// ---------------- quantum gate appliers (16-amp statevector in regs) ----------------
// wire w -> bit position (3 - w); bit 3 is MSB of the flat index (row-major reshape).

__device__ __forceinline__ void apply_rx(float* sr, float* si, int bit, float c, float s) {
    const int m = 1 << bit;
#pragma unroll
    for (int idx = 0; idx < 16; ++idx) {
        if (idx & m) continue;
        const int j = idx | m;
        float a0r = sr[idx], a0i = si[idx], a1r = sr[j], a1i = si[j];
        // U = [[c, -i s], [-i s, c]]
        sr[idx] = c * a0r + s * a1i;
        si[idx] = c * a0i - s * a1r;
        sr[j]   = c * a1r + s * a0i;
        si[j]   = c * a1i - s * a0r;
    }
}

__device__ __forceinline__ void apply_ry(float* sr, float* si, int bit, float c, float s) {
    const int m = 1 << bit;
#pragma unroll
    for (int idx = 0; idx < 16; ++idx) {
        if (idx & m) continue;
        const int j = idx | m;
        float a0r = sr[idx], a0i = si[idx], a1r = sr[j], a1i = si[j];
        // U = [[c, -s], [s, c]]
        sr[idx] = c * a0r - s * a1r;
        si[idx] = c * a0i - s * a1i;
        sr[j]   = s * a0r + c * a1r;
        si[j]   = s * a0i + c * a1i;
    }
}

__device__ __forceinline__ void apply_rz(float* sr, float* si, int bit, float c, float s) {
    const int m = 1 << bit;
#pragma unroll
    for (int idx = 0; idx < 16; ++idx) {
        if (idx & m) continue;
        const int j = idx | m;
        float a0r = sr[idx], a0i = si[idx], a1r = sr[j], a1i = si[j];
        // diag(e^{-i t/2}, e^{+i t/2}) ; c = cos(t/2), s = sin(t/2)
        sr[idx] = c * a0r + s * a0i;
        si[idx] = c * a0i - s * a0r;
        sr[j]   = c * a1r - s * a1i;
        si[j]   = c * a1i + s * a1r;
    }
}

__device__ __forceinline__ void apply_cnot(float* sr, float* si, int cw, int tw) {
    const int cb = 3 - cw, tb = 3 - tw;
#pragma unroll
    for (int idx = 0; idx < 16; ++idx) {
        if (((idx >> cb) & 1) && !((idx >> tb) & 1)) {
            const int j = idx | (1 << tb);
            float tr = sr[idx]; sr[idx] = sr[j]; sr[j] = tr;
            float ti = si[idx]; si[idx] = si[j]; si[j] = ti;
        }
    }
}

// ---------------- kernel 1: pool (6x6 mean) + encode angles -> fp32 in d_out ----------------
// 16 samples per block, 256 threads. x staged to LDS via coalesced float4 loads.
// Per-sample LDS stride padded to 145 float4 (580 floats).

__global__ __launch_bounds__(256) void pool_angles_kernel(
    const float4* __restrict__ x,           // fp32 x viewed as float4 (144 per sample)
    const float* __restrict__ enc_w,        // [4,16]
    const float* __restrict__ enc_b,        // [4]
    float* __restrict__ angles_out)         // [B,4] fp32 (= d_out)
{
    __shared__ float4 xbuf[16 * 145];       // 37120 B
    __shared__ float pooled[16][17];        // padded

    const int t = threadIdx.x;
    const int blk = blockIdx.x;

    // ---- stage 16 samples * 144 float4 = 2304 float4, coalesced ----
    const float4* src = x + (size_t)blk * 2304;
#pragma unroll
    for (int j = 0; j < 9; ++j) {
        const int f = t + 256 * j;          // 0..2303
        const int s = f / 144;              // 144 float4 per sample
        const int k = f - s * 144;
        xbuf[s * 145 + k] = src[f];
    }
    __syncthreads();

    // ---- pooling: thread t -> sample s = t>>4, pool cell p = t&15 ----
    {
        const int s = t >> 4;
        const int p = t & 15;
        const int pr = p >> 2, pc = p & 3;
        const float* sb = reinterpret_cast<const float*>(xbuf) + s * 580;
        const int base = pr * 144 + pc * 6; // (6*pr)*24 + 6*pc
        float acc = 0.0f;
#pragma unroll
        for (int r = 0; r < 6; ++r)
#pragma unroll
            for (int c = 0; c < 6; ++c)
                acc += sb[base + r * 24 + c];
        pooled[s][p] = acc * (1.0f / 36.0f);
    }
    __syncthreads();

    // ---- angles: 64 threads, t -> (sample s = t>>2, angle i = t&3) ----
    if (t < 64) {
        const int s = t >> 2, i = t & 3;
        float a = enc_b[i];
#pragma unroll
        for (int k = 0; k < 16; ++k)
            a += enc_w[i * 16 + k] * pooled[s][k];
        angles_out[(blk * 16 + s) * 4 + i] = a;
    }
}

// ---------------- kernel 2: circuit sim; fp32 angles -> fp32 z (in place) + BN partials ----------------
__global__ __launch_bounds__(256) void circuit_kernel(
    float4* __restrict__ io,                // [B] fp32 angle quads -> fp32 z quads (= d_out)
    const float* __restrict__ var_params,   // [2,4,3] = 24
    float* __restrict__ partials)           // [gridDim.x * 8]
{
    __shared__ float gc[24], gs[24];
    __shared__ float red[4 * 8];

    const int t = threadIdx.x;
    if (t < 24) {
        float th = 0.5f * var_params[t];
        float s, c;
        __sincosf(th, &s, &c);
        gc[t] = c; gs[t] = s;
    }
    __syncthreads();

    const int b = blockIdx.x * 256 + t;
    const float4 a4 = io[b];
    const float av[4] = {a4.x, a4.y, a4.z, a4.w};

    float sr[16], si[16];
#pragma unroll
    for (int i = 0; i < 16; ++i) { sr[i] = 0.0f; si[i] = 0.0f; }
    sr[0] = 1.0f;

    // encoding RX(angle_w) on wire w
#pragma unroll
    for (int w = 0; w < 4; ++w) {
        float s, c;
        __sincosf(0.5f * av[w], &s, &c);
        apply_rx(sr, si, 3 - w, c, s);
    }

#pragma unroll
    for (int d = 0; d < 2; ++d) {
#pragma unroll
        for (int w = 0; w < 4; ++w) {
            const int base = d * 12 + w * 3;
            apply_rx(sr, si, 3 - w, gc[base + 0], gs[base + 0]);
            apply_ry(sr, si, 3 - w, gc[base + 1], gs[base + 1]);
            apply_rz(sr, si, 3 - w, gc[base + 2], gs[base + 2]);
        }
        apply_cnot(sr, si, 0, 1);
        apply_cnot(sr, si, 1, 2);
        apply_cnot(sr, si, 2, 3);
        apply_cnot(sr, si, 3, 0);
    }

    // probabilities and Z expectations
    float pr16[16];
#pragma unroll
    for (int i = 0; i < 16; ++i) pr16[i] = sr[i] * sr[i] + si[i] * si[i];

    float z[4];
#pragma unroll
    for (int w = 0; w < 4; ++w) {
        const int bit = 3 - w;
        float acc = 0.0f;
#pragma unroll
        for (int i = 0; i < 16; ++i)
            acc += ((i >> bit) & 1) ? -pr16[i] : pr16[i];
        z[w] = acc;
    }

    io[b] = make_float4(z[0], z[1], z[2], z[3]);

    // block reduction of sum(z) and sum(z^2) -> per-block partials (deterministic, no atomics)
    float vals[8] = {z[0], z[1], z[2], z[3],
                     z[0] * z[0], z[1] * z[1], z[2] * z[2], z[3] * z[3]};
#pragma unroll
    for (int j = 0; j < 8; ++j) {
        float v = vals[j];
#pragma unroll
        for (int off = 32; off >= 1; off >>= 1)
            v += __shfl_down(v, off, 64);
        if ((t & 63) == 0) red[(t >> 6) * 8 + j] = v;
    }
    __syncthreads();
    if (t < 8) {
        partials[blockIdx.x * 8 + t] = red[t] + red[8 + t] + red[16 + t] + red[24 + t];
    }
}

// ---------------- kernel 3: batchnorm finalize; fp32 z -> fp32 out (in place) ----------------
__global__ __launch_bounds__(256) void bn_kernel(
    float4* __restrict__ io,                // [B] fp32 z quads -> fp32 out quads (= d_out)
    const float* __restrict__ partials,     // [nPartialRows * 8]
    const float* __restrict__ gamma,
    const float* __restrict__ beta,
    int nPartialRows, int B)
{
    __shared__ float stats[8];
    const int t = threadIdx.x;

    if (t < 64) {
        float part[8];
#pragma unroll
        for (int j = 0; j < 8; ++j) part[j] = 0.0f;
        for (int r = t; r < nPartialRows; r += 64) {
            const float* row = partials + r * 8;
#pragma unroll
            for (int j = 0; j < 8; ++j) part[j] += row[j];
        }
#pragma unroll
        for (int j = 0; j < 8; ++j) {
            float v = part[j];
#pragma unroll
            for (int off = 32; off >= 1; off >>= 1)
                v += __shfl_down(v, off, 64);
            if (t == 0) stats[j] = v;
        }
    }
    __syncthreads();

    const int b = blockIdx.x * 256 + t;
    const float invB = 1.0f / (float)B;
    const float4 z4 = io[b];
    const float zz[4] = {z4.x, z4.y, z4.z, z4.w};

    float res[4];
#pragma unroll
    for (int i = 0; i < 4; ++i) {
        const float mean = stats[i] * invB;
        float var = stats[4 + i] * invB - mean * mean;
        var = fmaxf(var, 0.0f);
        const float scale = gamma[i] * rsqrtf(var + 1e-5f);
        res[i] = (zz[i] - mean) * scale + beta[i];
    }
    io[b] = make_float4(res[0], res[1], res[2], res[3]);
}

// ---------------- launch ----------------
extern "C" void kernel_launch(void* const* d_in, const int* in_sizes, int n_in,
                              void* d_out, int out_size, void* d_ws, size_t ws_size,
                              hipStream_t stream) {
    const float4* x = (const float4*)d_in[0];
    const float* enc_w = (const float*)d_in[1];
    const float* enc_b = (const float*)d_in[2];
    const float* var_params = (const float*)d_in[3];
    const float* gamma = (const float*)d_in[4];
    const float* beta = (const float*)d_in[5];

    const int B = in_sizes[0] / 576;            // 65536
    float* io = (float*)d_out;                  // B*4 floats (angles -> z -> out, in place)
    float* partials = (float*)d_ws;             // 256*8 floats = 8 KB only

    const int nCircuitBlocks = B / 256;         // 256

    pool_angles_kernel<<<B / 16, 256, 0, stream>>>(x, enc_w, enc_b, io);
    circuit_kernel<<<nCircuitBlocks, 256, 0, stream>>>((float4*)io, var_params, partials);
    bn_kernel<<<nCircuitBlocks, 256, 0, stream>>>((float4*)io, partials, gamma, beta,
                                                  nCircuitBlocks, B);
}

// Round 4
// 225.621 us; speedup vs baseline: 1.0035x; 1.0035x over previous
//
#include <hip/hip_runtime.h>

// ---------------- quantum gate appliers (16-amp statevector in regs) ----------------
// wire w -> bit position (3 - w); bit 3 is MSB of the flat index (row-major reshape).

__device__ __forceinline__ void apply_rx(float* sr, float* si, int bit, float c, float s) {
    const int m = 1 << bit;
#pragma unroll
    for (int idx = 0; idx < 16; ++idx) {
        if (idx & m) continue;
        const int j = idx | m;
        float a0r = sr[idx], a0i = si[idx], a1r = sr[j], a1i = si[j];
        // U = [[c, -i s], [-i s, c]]
        sr[idx] = c * a0r + s * a1i;
        si[idx] = c * a0i - s * a1r;
        sr[j]   = c * a1r + s * a0i;
        si[j]   = c * a1i - s * a0r;
    }
}

__device__ __forceinline__ void apply_ry(float* sr, float* si, int bit, float c, float s) {
    const int m = 1 << bit;
#pragma unroll
    for (int idx = 0; idx < 16; ++idx) {
        if (idx & m) continue;
        const int j = idx | m;
        float a0r = sr[idx], a0i = si[idx], a1r = sr[j], a1i = si[j];
        // U = [[c, -s], [s, c]]
        sr[idx] = c * a0r - s * a1r;
        si[idx] = c * a0i - s * a1i;
        sr[j]   = s * a0r + c * a1r;
        si[j]   = s * a0i + c * a1i;
    }
}

__device__ __forceinline__ void apply_rz(float* sr, float* si, int bit, float c, float s) {
    const int m = 1 << bit;
#pragma unroll
    for (int idx = 0; idx < 16; ++idx) {
        if (idx & m) continue;
        const int j = idx | m;
        float a0r = sr[idx], a0i = si[idx], a1r = sr[j], a1i = si[j];
        // diag(e^{-i t/2}, e^{+i t/2}) ; c = cos(t/2), s = sin(t/2)
        sr[idx] = c * a0r + s * a0i;
        si[idx] = c * a0i - s * a0r;
        sr[j]   = c * a1r - s * a1i;
        si[j]   = c * a1i + s * a1r;
    }
}

__device__ __forceinline__ void apply_cnot(float* sr, float* si, int cw, int tw) {
    const int cb = 3 - cw, tb = 3 - tw;
#pragma unroll
    for (int idx = 0; idx < 16; ++idx) {
        if (((idx >> cb) & 1) && !((idx >> tb) & 1)) {
            const int j = idx | (1 << tb);
            float tr = sr[idx]; sr[idx] = sr[j]; sr[j] = tr;
            float ti = si[idx]; si[idx] = si[j]; si[j] = ti;
        }
    }
}

// ---------------- kernel 1: pool (6x6 mean) + encode angles -> fp32 in d_out ----------------
// 8 samples per block, 256 threads, 18.4 KB LDS -> 8 blocks/CU = 32 waves/CU (max occupancy).
// Staging is an exact division-free copy; pooling uses all 256 threads (half-cell each).

__global__ __launch_bounds__(256) void pool_angles_kernel(
    const float4* __restrict__ x,           // fp32 x viewed as float4 (144 per sample)
    const float* __restrict__ enc_w,        // [4,16]
    const float* __restrict__ enc_b,        // [4]
    float* __restrict__ angles_out)         // [B,4] fp32 (= d_out)
{
    __shared__ float4 xbuf[8 * 144];        // 18432 B, exact copy of 8 samples
    __shared__ float pooled[8][17];         // padded

    const int t = threadIdx.x;
    const int blk = blockIdx.x;

    // ---- stage 8 samples * 144 float4 = 1152 float4, coalesced, no div ----
    const float4* src = x + (size_t)blk * 1152;
#pragma unroll
    for (int j = 0; j < 4; ++j)
        xbuf[t + 256 * j] = src[t + 256 * j];
    if (t < 128)
        xbuf[1024 + t] = src[1024 + t];
    __syncthreads();

    // ---- pooling: 256 threads = 8 samples x 16 cells x 2 halves (3 rows each) ----
    {
        const int s = t >> 5;               // sample 0..7
        const int q = t & 31;
        const int cell = q & 15;            // pool cell 0..15 (pr*4+pc)
        const int half = q >> 4;            // 0: rows 0-2, 1: rows 3-5
        const int pr = cell >> 2, pc = cell & 3;
        const float* sb = reinterpret_cast<const float*>(xbuf) + s * 576;
        const int base = pr * 144 + pc * 6 + half * 72;
        float acc = 0.0f;
        // row order rotated by pr to break pr-parity bank aliasing
#pragma unroll
        for (int r0 = 0; r0 < 3; ++r0) {
            int r = r0 + (pr & 3);
            if (r >= 3) r -= 3;
            const int rowbase = base + r * 24;
#pragma unroll
            for (int c = 0; c < 6; ++c)
                acc += sb[rowbase + c];
        }
        acc += __shfl_xor(acc, 16, 64);     // combine the two halves (same wave)
        if (half == 0)
            pooled[s][cell] = acc * (1.0f / 36.0f);
    }
    __syncthreads();

    // ---- angles: 32 threads, t -> (sample s = t>>2, angle i = t&3) ----
    if (t < 32) {
        const int s = t >> 2, i = t & 3;
        float a = enc_b[i];
#pragma unroll
        for (int k = 0; k < 16; ++k)
            a += enc_w[i * 16 + k] * pooled[s][k];
        angles_out[(blk * 8 + s) * 4 + i] = a;
    }
}

// ---------------- kernel 2: circuit sim; fp32 angles -> fp32 z (in place) + BN partials ----------------
__global__ __launch_bounds__(256) void circuit_kernel(
    float4* __restrict__ io,                // [B] fp32 angle quads -> fp32 z quads (= d_out)
    const float* __restrict__ var_params,   // [2,4,3] = 24
    float* __restrict__ partials)           // [gridDim.x * 8]
{
    __shared__ float gc[24], gs[24];
    __shared__ float red[4 * 8];

    const int t = threadIdx.x;
    if (t < 24) {
        float th = 0.5f * var_params[t];
        float s, c;
        __sincosf(th, &s, &c);
        gc[t] = c; gs[t] = s;
    }
    __syncthreads();

    const int b = blockIdx.x * 256 + t;
    const float4 a4 = io[b];
    const float av[4] = {a4.x, a4.y, a4.z, a4.w};

    float sr[16], si[16];
#pragma unroll
    for (int i = 0; i < 16; ++i) { sr[i] = 0.0f; si[i] = 0.0f; }
    sr[0] = 1.0f;

    // encoding RX(angle_w) on wire w
#pragma unroll
    for (int w = 0; w < 4; ++w) {
        float s, c;
        __sincosf(0.5f * av[w], &s, &c);
        apply_rx(sr, si, 3 - w, c, s);
    }

#pragma unroll
    for (int d = 0; d < 2; ++d) {
#pragma unroll
        for (int w = 0; w < 4; ++w) {
            const int base = d * 12 + w * 3;
            apply_rx(sr, si, 3 - w, gc[base + 0], gs[base + 0]);
            apply_ry(sr, si, 3 - w, gc[base + 1], gs[base + 1]);
            apply_rz(sr, si, 3 - w, gc[base + 2], gs[base + 2]);
        }
        apply_cnot(sr, si, 0, 1);
        apply_cnot(sr, si, 1, 2);
        apply_cnot(sr, si, 2, 3);
        apply_cnot(sr, si, 3, 0);
    }

    // probabilities and Z expectations
    float pr16[16];
#pragma unroll
    for (int i = 0; i < 16; ++i) pr16[i] = sr[i] * sr[i] + si[i] * si[i];

    float z[4];
#pragma unroll
    for (int w = 0; w < 4; ++w) {
        const int bit = 3 - w;
        float acc = 0.0f;
#pragma unroll
        for (int i = 0; i < 16; ++i)
            acc += ((i >> bit) & 1) ? -pr16[i] : pr16[i];
        z[w] = acc;
    }

    io[b] = make_float4(z[0], z[1], z[2], z[3]);

    // block reduction of sum(z) and sum(z^2) -> per-block partials (deterministic, no atomics)
    float vals[8] = {z[0], z[1], z[2], z[3],
                     z[0] * z[0], z[1] * z[1], z[2] * z[2], z[3] * z[3]};
#pragma unroll
    for (int j = 0; j < 8; ++j) {
        float v = vals[j];
#pragma unroll
        for (int off = 32; off >= 1; off >>= 1)
            v += __shfl_down(v, off, 64);
        if ((t & 63) == 0) red[(t >> 6) * 8 + j] = v;
    }
    __syncthreads();
    if (t < 8) {
        partials[blockIdx.x * 8 + t] = red[t] + red[8 + t] + red[16 + t] + red[24 + t];
    }
}

// ---------------- kernel 3: batchnorm finalize; fp32 z -> fp32 out (in place) ----------------
__global__ __launch_bounds__(256) void bn_kernel(
    float4* __restrict__ io,                // [B] fp32 z quads -> fp32 out quads (= d_out)
    const float* __restrict__ partials,     // [nPartialRows * 8]
    const float* __restrict__ gamma,
    const float* __restrict__ beta,
    int nPartialRows, int B)
{
    __shared__ float stats[8];
    const int t = threadIdx.x;

    if (t < 64) {
        float part[8];
#pragma unroll
        for (int j = 0; j < 8; ++j) part[j] = 0.0f;
        for (int r = t; r < nPartialRows; r += 64) {
            const float* row = partials + r * 8;
#pragma unroll
            for (int j = 0; j < 8; ++j) part[j] += row[j];
        }
#pragma unroll
        for (int j = 0; j < 8; ++j) {
            float v = part[j];
#pragma unroll
            for (int off = 32; off >= 1; off >>= 1)
                v += __shfl_down(v, off, 64);
            if (t == 0) stats[j] = v;
        }
    }
    __syncthreads();

    const int b = blockIdx.x * 256 + t;
    const float invB = 1.0f / (float)B;
    const float4 z4 = io[b];
    const float zz[4] = {z4.x, z4.y, z4.z, z4.w};

    float res[4];
#pragma unroll
    for (int i = 0; i < 4; ++i) {
        const float mean = stats[i] * invB;
        float var = stats[4 + i] * invB - mean * mean;
        var = fmaxf(var, 0.0f);
        const float scale = gamma[i] * rsqrtf(var + 1e-5f);
        res[i] = (zz[i] - mean) * scale + beta[i];
    }
    io[b] = make_float4(res[0], res[1], res[2], res[3]);
}

// ---------------- launch ----------------
extern "C" void kernel_launch(void* const* d_in, const int* in_sizes, int n_in,
                              void* d_out, int out_size, void* d_ws, size_t ws_size,
                              hipStream_t stream) {
    const float4* x = (const float4*)d_in[0];
    const float* enc_w = (const float*)d_in[1];
    const float* enc_b = (const float*)d_in[2];
    const float* var_params = (const float*)d_in[3];
    const float* gamma = (const float*)d_in[4];
    const float* beta = (const float*)d_in[5];

    const int B = in_sizes[0] / 576;            // 65536
    float* io = (float*)d_out;                  // B*4 floats (angles -> z -> out, in place)
    float* partials = (float*)d_ws;             // 256*8 floats = 8 KB only

    const int nCircuitBlocks = B / 256;         // 256

    pool_angles_kernel<<<B / 8, 256, 0, stream>>>(x, enc_w, enc_b, io);
    circuit_kernel<<<nCircuitBlocks, 256, 0, stream>>>((float4*)io, var_params, partials);
    bn_kernel<<<nCircuitBlocks, 256, 0, stream>>>((float4*)io, partials, gamma, beta,
                                                  nCircuitBlocks, B);
}